// Round 11
// baseline (5094.902 us; speedup 1.0000x reference)
//
#include <hip/hip_runtime.h>

#define NB 32
#define NPTS 131072
#define KSAMP 2048
#define NPART 8
#define TPB 512
#define NPT 32                    // points per thread = NPTS/(NPART*TPB)
#define PART_PTS (NPTS / NPART)   // 16384

// One batch = 8 blocks x 512 threads (proven cooperative grid: 256 blocks =
// 1 block/CU).
//
// R6-R10 finding: the register allocator refuses to keep the 96 coord floats
// per thread in VGPRs (VGPR_Count stuck at 88-92 across arrays / named
// scalars / asm pins / waves_per_eu(2,2)), re-streaming ~50MB/step through
// the cache hierarchy. R11 removes the RA's discretion: (x,y) live in a
// 128KB LDS array (guaranteed on-CU residency, conflict-free stride-8B
// ds_read_b64, each thread reads only its own entries -> no extra barriers);
// z + md2 remain as 64 named-scalar VGPRs (within the RA's demonstrated
// comfort zone). LDS 131KB/block -> 1 block/CU, same occupancy as before.
//
// Scan in d^2 domain (R10-validated bit-exact):
//   d2  = fma(dz,dz, fma(dx,dx, dy*dy))     (R4-validated contraction)
//   md2 = fminf(md2, d2)
// Per-thread argmax over md2 (strict >, ascending J = first-index), then ONE
// CR sqrt converts the thread winner to the reference's sd domain; the
// cross-lane/cross-block tree compares (sd_bits<<32)|(131071-n) == jnp.argmax
// value+first-index semantics over min_d.
//
// Sync per step (R6-proven): wave shfl max -> LDS -> wave0 cross-wave max ->
// tagged publish (agent store) -> wave0 spins on 64B row until all 8 tags
// match -> LDS broadcast -> barrier. No atomics, no ws zeroing (tags 1..2047
// disambiguate 0xAA poison (tag 0x5555) / stale replay data, which is
// bitwise-identical by determinism anyway).

#define RPT32(X) X(0)X(1)X(2)X(3)X(4)X(5)X(6)X(7)X(8)X(9)X(10)X(11)X(12) \
  X(13)X(14)X(15)X(16)X(17)X(18)X(19)X(20)X(21)X(22)X(23)X(24)X(25)X(26) \
  X(27)X(28)X(29)X(30)X(31)

__global__ __launch_bounds__(TPB)
__attribute__((amdgpu_waves_per_eu(2, 2)))
void fps_kernel(
    const float* __restrict__ x, const int* __restrict__ start,
    int* __restrict__ out, unsigned long long* __restrict__ slot)
{
  #pragma clang fp contract(off)
  const int blk  = blockIdx.x;
  // XCD-clustered: all 8 parts of a batch share blk&7 (same XCD under
  // round-robin dispatch) -> sync row + x slice get L2 locality.
  const int xcd  = blk & 7;
  const int j    = blk >> 3;          // 0..31
  const int b    = xcd * 4 + (j & 3); // 0..31
  const int part = j >> 2;            // 0..7
  const int tid  = threadIdx.x;
  const int lane = tid & 63;
  const int wave = tid >> 6;

  const float* xb = x + (size_t)b * (NPTS * 3);

  // start_idx dtype hedge: int64 (LE, <2^31) => zeros at odd int32 slots.
  bool is64 = true;
  #pragma unroll 1
  for (int i = 1; i < 32; i += 2) {
    if (start[i] != 0) { is64 = false; break; }
  }
  int cur = is64 ? start[2 * b] : start[b];

  const int base = part * PART_PTS + tid;

  // (x,y) of this block's 16384-point slice: 128KB LDS, point p at pxy_s[p],
  // read only by the owning thread (p = tid + J*TPB) -> no sync needed.
  __shared__ float2 pxy_s[PART_PTS];
  __shared__ unsigned long long wred[TPB / 64];
  __shared__ int snext;

  // z + md2: 64 named scalars in VGPRs.
  #define DECLP(J) float pz##J, md2##J;
  RPT32(DECLP)
  #define INITP(J) { const int n = base + (J) * TPB;                 \
      pxy_s[tid + (J) * TPB] = make_float2(xb[3*n], xb[3*n+1]);      \
      pz##J = xb[3*n+2];  md2##J = __builtin_inff(); }
  RPT32(INITP)
  // Pin z into VGPRs: opaque copy forbids load-rematerialization.
  #define PINP(J) asm("" : "+v"(pz##J));
  RPT32(PINP)

  if (part == 0 && tid == 0) out[b * KSAMP] = cur;  // scan emits idx BEFORE update

  float cx = xb[3 * (size_t)cur + 0];
  float cy = xb[3 * (size_t)cur + 1];
  float cz = xb[3 * (size_t)cur + 2];

  unsigned long long* const srow0 = slot + (size_t)b * 2 * NPART;  // [b][2][8]

  for (int k = 0; k < KSAMP - 1; ++k) {
    float bestv = -1.0f;   // d^2 domain
    int   bestn = 0;
    #define SCANP(J) {                                              \
      const float2 q = pxy_s[tid + (J) * TPB];                      \
      const float dx = q.x - cx;                                    \
      const float dy = q.y - cy;                                    \
      const float dz = pz##J - cz;                                  \
      const float d2 = fmaf(dz, dz, fmaf(dx, dx, dy * dy));         \
      const float m  = fminf(md2##J, d2);                           \
      md2##J = m;                                                   \
      if (m > bestv) { bestv = m; bestn = base + (J) * TPB; }       \
    }
    RPT32(SCANP)

    // ONE CR sqrt per thread: convert winner to the reference's sd domain.
    const float sdw = sqrtf(bestv);

    // pack: higher sd wins; equal sd -> smaller index wins (131071-n).
    // index field bits 0..16; bits 17..31 stay 0 for the step tag.
    unsigned long long key =
        ((unsigned long long)__float_as_uint(sdw) << 32) |
        (unsigned int)(NPTS - 1 - bestn);

    #pragma unroll
    for (int off = 32; off >= 1; off >>= 1) {
      unsigned long long o = __shfl_xor(key, off, 64);
      if (o > key) key = o;
    }
    if (lane == 0) wred[wave] = key;
    __syncthreads();

    if (wave == 0) {
      // cross-wave max: lanes hold wred[lane&7]; 3 xor steps reduce each
      // aligned 8-group (all groups identical) -> block max on all lanes.
      unsigned long long v = wred[lane & 7];
      #pragma unroll
      for (int off = 4; off >= 1; off >>= 1) {
        unsigned long long o = __shfl_xor(v, off, 64);
        if (o > v) v = o;
      }

      const unsigned tag = (unsigned)(k + 1);     // 1..2047, never 0x5555 poison
      unsigned long long* const row = srow0 + (unsigned)(k & 1) * NPART;
      if (lane == 0)
        __hip_atomic_store(&row[part], v | ((unsigned long long)tag << 17),
                           __ATOMIC_RELAXED, __HIP_MEMORY_SCOPE_AGENT);

      // parallel spin on the 64B row until all 8 tags match this step.
      unsigned long long g;
      do {
        g = __hip_atomic_load(&row[lane & (NPART - 1)], __ATOMIC_RELAXED,
                              __HIP_MEMORY_SCOPE_AGENT);
      } while (__ballot(((unsigned)(g >> 17) & 0x7FFFu) == tag) != ~0ull);

      // max over 8 slots (each aligned 8-group identical): 3 xor steps.
      #pragma unroll
      for (int off = 4; off >= 1; off >>= 1) {
        unsigned long long o = __shfl_xor(g, off, 64);
        if (o > g) g = o;
      }
      const int nidx = NPTS - 1 - (int)(g & 0x1FFFFu);
      if (lane == 0) {
        snext = nidx;
        if (part == 0) out[b * KSAMP + k + 1] = nidx;
      }
    }
    __syncthreads();

    const int nidx = snext;
    cx = xb[3 * (size_t)nidx + 0];
    cy = xb[3 * (size_t)nidx + 1];
    cz = xb[3 * (size_t)nidx + 2];
  }
}

extern "C" void kernel_launch(void* const* d_in, const int* in_sizes, int n_in,
                              void* d_out, int out_size, void* d_ws, size_t ws_size,
                              hipStream_t stream) {
  const float* x     = (const float*)d_in[0];
  const int*   start = (const int*)d_in[1];
  int*         out   = (int*)d_out;
  unsigned long long* slot = (unsigned long long*)d_ws;  // [32][2][8] u64 = 4KB

  // No memset needed: step tags (1..2047 in bits 17..31) disambiguate the
  // 0xAA poison (tag 0x5555) and stale values from prior replays (which are
  // bitwise-identical across deterministic replays anyway).
  void* args[] = {(void*)&x, (void*)&start, (void*)&out, (void*)&slot};
  hipLaunchCooperativeKernel((void*)fps_kernel, dim3(NB * NPART), dim3(TPB),
                             args, 0, stream);
}

// Round 13
// 4781.292 us; speedup vs baseline: 1.0656x; 1.0656x over previous
//
#include <hip/hip_runtime.h>

#define NB 32
#define NPTS 131072
#define KSAMP 2048
#define NPART 8
#define TPB 512
#define NPT 32                    // points per thread = NPTS/(NPART*TPB)
#define PART_PTS (NPTS / NPART)   // 16384

// One batch = 8 blocks x 512 threads (proven cooperative grid: 256 blocks =
// 1 block/CU). Each thread owns 32 points as named scalars.
//
// R6-R11 findings: (1) scan is VALU-ISSUE-bound on load+address arithmetic
// (R11 cut L2 traffic 2/3 -> slower; issue count unchanged); (2) the RA
// rematerializes invariant coord loads inside the k-loop no matter how they
// are pinned OUTSIDE it (VGPR_Count stuck at 88-92). Fix: empty
// asm volatile pins at the TOP OF EVERY k-ITERATION. The next use of each
// coord after iter k's pin is iter k+1's pin -> values must be loop-carried
// in VGPRs; opaque asm cannot be rematerialized through. Budget fits:
// waves_per_eu(2,2) => 256 regs/wave, need ~160 (96 coords + 32 md2 + temps).
//
// Scan in d^2 domain (R10-validated bit-exact):
//   d2  = fma(dz,dz, fma(dx,dx, dy*dy))     (R4-validated contraction)
//   md2 = fminf(md2, d2)
// Per-thread argmax over md2 (strict >, ascending J = first-index), then ONE
// CR sqrt converts the thread winner to the reference's sd domain; the
// cross-lane/cross-block tree compares (sd_bits<<32)|(131071-n) == jnp.argmax
// value+first-index semantics over min_d.
//
// Sync per step (R6-proven): wave shfl max -> LDS -> wave0 cross-wave max ->
// tagged publish (agent store) -> wave0 spins on 64B row until all 8 tags
// match -> LDS broadcast -> barrier. No atomics, no ws zeroing (tags 1..2047
// disambiguate 0xAA poison (tag 0x5555) / stale replay data, which is
// bitwise-identical by determinism anyway).

#define RPT32(X) X(0)X(1)X(2)X(3)X(4)X(5)X(6)X(7)X(8)X(9)X(10)X(11)X(12) \
  X(13)X(14)X(15)X(16)X(17)X(18)X(19)X(20)X(21)X(22)X(23)X(24)X(25)X(26) \
  X(27)X(28)X(29)X(30)X(31)

#define OPSA(P) "+v"(P##0), "+v"(P##1), "+v"(P##2), "+v"(P##3), \
  "+v"(P##4), "+v"(P##5), "+v"(P##6), "+v"(P##7)
#define OPSB(P) "+v"(P##8), "+v"(P##9), "+v"(P##10), "+v"(P##11), \
  "+v"(P##12), "+v"(P##13), "+v"(P##14), "+v"(P##15)
#define OPSC(P) "+v"(P##16), "+v"(P##17), "+v"(P##18), "+v"(P##19), \
  "+v"(P##20), "+v"(P##21), "+v"(P##22), "+v"(P##23)
#define OPSD(P) "+v"(P##24), "+v"(P##25), "+v"(P##26), "+v"(P##27), \
  "+v"(P##28), "+v"(P##29), "+v"(P##30), "+v"(P##31)
#define PIN32(P) asm volatile("" : OPSA(P), OPSB(P), OPSC(P), OPSD(P));

__global__ __launch_bounds__(TPB)
__attribute__((amdgpu_waves_per_eu(2, 2)))
void fps_kernel(
    const float* __restrict__ x, const int* __restrict__ start,
    int* __restrict__ out, unsigned long long* __restrict__ slot)
{
  #pragma clang fp contract(off)
  const int blk  = blockIdx.x;
  // XCD-clustered: all 8 parts of a batch share blk&7 (same XCD under
  // round-robin dispatch) -> sync row + x slice get L2 locality.
  const int xcd  = blk & 7;
  const int j    = blk >> 3;          // 0..31
  const int b    = xcd * 4 + (j & 3); // 0..31
  const int part = j >> 2;            // 0..7
  const int tid  = threadIdx.x;
  const int lane = tid & 63;
  const int wave = tid >> 6;

  const float* xb = x + (size_t)b * (NPTS * 3);

  // start_idx dtype hedge: int64 (LE, <2^31) => zeros at odd int32 slots.
  bool is64 = true;
  #pragma unroll 1
  for (int i = 1; i < 32; i += 2) {
    if (start[i] != 0) { is64 = false; break; }
  }
  int cur = is64 ? start[2 * b] : start[b];

  const int base = part * PART_PTS + tid;

  // 128 named scalars: px/py/pz coords + md2 running min-dist^2.
  #define DECLP(J) float px##J, py##J, pz##J, md2##J;
  RPT32(DECLP)
  #define INITP(J) { const int n = base + (J) * TPB;          \
      px##J = xb[3*n]; py##J = xb[3*n+1]; pz##J = xb[3*n+2];  \
      md2##J = __builtin_inff(); }
  RPT32(INITP)

  __shared__ unsigned long long wred[TPB / 64];
  __shared__ int snext;

  if (part == 0 && tid == 0) out[b * KSAMP] = cur;  // scan emits idx BEFORE update

  float cx = xb[3 * (size_t)cur + 0];
  float cy = xb[3 * (size_t)cur + 1];
  float cz = xb[3 * (size_t)cur + 2];

  unsigned long long* const srow0 = slot + (size_t)b * 2 * NPART;  // [b][2][8]

  for (int k = 0; k < KSAMP - 1; ++k) {
    // In-loop opaque pins: coords' next use after iter k's pin is iter
    // k+1's pin -> must be loop-carried in VGPRs; remat impossible.
    PIN32(px)
    PIN32(py)
    PIN32(pz)

    float bestv = -1.0f;   // d^2 domain
    int   bestn = 0;
    #define SCANP(J) {                                              \
      const float dx = px##J - cx;                                  \
      const float dy = py##J - cy;                                  \
      const float dz = pz##J - cz;                                  \
      const float d2 = fmaf(dz, dz, fmaf(dx, dx, dy * dy));         \
      const float m  = fminf(md2##J, d2);                           \
      md2##J = m;                                                   \
      if (m > bestv) { bestv = m; bestn = base + (J) * TPB; }       \
    }
    RPT32(SCANP)

    // ONE CR sqrt per thread: convert winner to the reference's sd domain.
    const float sdw = sqrtf(bestv);

    // pack: higher sd wins; equal sd -> smaller index wins (131071-n).
    // index field bits 0..16; bits 17..31 stay 0 for the step tag.
    unsigned long long key =
        ((unsigned long long)__float_as_uint(sdw) << 32) |
        (unsigned int)(NPTS - 1 - bestn);

    #pragma unroll
    for (int off = 32; off >= 1; off >>= 1) {
      unsigned long long o = __shfl_xor(key, off, 64);
      if (o > key) key = o;
    }
    if (lane == 0) wred[wave] = key;
    __syncthreads();

    if (wave == 0) {
      // cross-wave max: lanes hold wred[lane&7]; 3 xor steps reduce each
      // aligned 8-group (all groups identical) -> block max on all lanes.
      unsigned long long v = wred[lane & 7];
      #pragma unroll
      for (int off = 4; off >= 1; off >>= 1) {
        unsigned long long o = __shfl_xor(v, off, 64);
        if (o > v) v = o;
      }

      const unsigned tag = (unsigned)(k + 1);     // 1..2047, never 0x5555 poison
      unsigned long long* const row = srow0 + (unsigned)(k & 1) * NPART;
      if (lane == 0)
        __hip_atomic_store(&row[part], v | ((unsigned long long)tag << 17),
                           __ATOMIC_RELAXED, __HIP_MEMORY_SCOPE_AGENT);

      // parallel spin on the 64B row until all 8 tags match this step.
      unsigned long long g;
      do {
        g = __hip_atomic_load(&row[lane & (NPART - 1)], __ATOMIC_RELAXED,
                              __HIP_MEMORY_SCOPE_AGENT);
      } while (__ballot(((unsigned)(g >> 17) & 0x7FFFu) == tag) != ~0ull);

      // max over 8 slots (each aligned 8-group identical): 3 xor steps.
      #pragma unroll
      for (int off = 4; off >= 1; off >>= 1) {
        unsigned long long o = __shfl_xor(g, off, 64);
        if (o > g) g = o;
      }
      const int nidx = NPTS - 1 - (int)(g & 0x1FFFFu);
      if (lane == 0) {
        snext = nidx;
        if (part == 0) out[b * KSAMP + k + 1] = nidx;
      }
    }
    __syncthreads();

    const int nidx = snext;
    cx = xb[3 * (size_t)nidx + 0];
    cy = xb[3 * (size_t)nidx + 1];
    cz = xb[3 * (size_t)nidx + 2];
  }
}

extern "C" void kernel_launch(void* const* d_in, const int* in_sizes, int n_in,
                              void* d_out, int out_size, void* d_ws, size_t ws_size,
                              hipStream_t stream) {
  const float* x     = (const float*)d_in[0];
  const int*   start = (const int*)d_in[1];
  int*         out   = (int*)d_out;
  unsigned long long* slot = (unsigned long long*)d_ws;  // [32][2][8] u64 = 4KB

  // No memset needed: step tags (1..2047 in bits 17..31) disambiguate the
  // 0xAA poison (tag 0x5555) and stale values from prior replays (which are
  // bitwise-identical across deterministic replays anyway).
  void* args[] = {(void*)&x, (void*)&start, (void*)&out, (void*)&slot};
  hipLaunchCooperativeKernel((void*)fps_kernel, dim3(NB * NPART), dim3(TPB),
                             args, 0, stream);
}

// Round 14
// 4644.075 us; speedup vs baseline: 1.0971x; 1.0295x over previous
//
#include <hip/hip_runtime.h>

#define NB 32
#define NPTS 131072
#define KSAMP 2048
#define TPB 512

// Two kernels, host picks by occupancy query (deterministic):
//  fps16: 16 parts/batch, NPT=16, grid 512 = 2 blocks/CU. 64 state floats
//         per thread (inside the RA's proven ~92-VGPR comfort zone), and
//         co-resident blocks hide each other's sync/reload stalls.
//  fps32: R10 fallback (proven 4649us): 8 parts/batch, NPT=32, grid 256.
//
// Shared numerics (validated bit-exact R4/R10):
//   d2  = fma(dz,dz, fma(dx,dx, dy*dy))   (LLVM-canonical contraction)
//   md2 = fminf(md2, d2)  (d^2 domain; ONE CR sqrt per thread converts the
//         winner to the ref's sd domain; CR-sqrt monotone => bitwise equal
//         to ref's iterated min(min_d, sqrt(dist)))
//   argmax first-index ties at every level: strict > ascending J in-thread;
//   packed (sd_bits<<32)|(131071-n) u64-max across lanes/waves/blocks.
//
// Sync per step (R6-proven): wave shfl max -> LDS -> wave0 cross-wave max ->
// tagged publish (agent store) -> wave0 spins on slot row until all tags
// match -> LDS broadcast -> barrier. No atomics, no ws zeroing (tags 1..2047
// disambiguate 0xAA poison (tag 0x5555) / stale replay data; double-buffered
// rows kill WAR: row k&1 is rewritten only at k+2, after all parts left k).

#define RPT16(X) X(0)X(1)X(2)X(3)X(4)X(5)X(6)X(7)X(8)X(9)X(10)X(11)X(12) \
  X(13)X(14)X(15)
#define RPT32(X) RPT16(X) X(16)X(17)X(18)X(19)X(20)X(21)X(22)X(23)X(24) \
  X(25)X(26)X(27)X(28)X(29)X(30)X(31)

#define DECLP(J) float px##J, py##J, pz##J, md2##J;
#define INITP(J) { const int n = base + (J) * TPB;          \
    px##J = xb[3*n]; py##J = xb[3*n+1]; pz##J = xb[3*n+2];  \
    md2##J = __builtin_inff(); }
#define SCANP(J) {                                              \
    const float dx = px##J - cx;                                \
    const float dy = py##J - cy;                                \
    const float dz = pz##J - cz;                                \
    const float d2 = fmaf(dz, dz, fmaf(dx, dx, dy * dy));       \
    const float m  = fminf(md2##J, d2);                         \
    md2##J = m;                                                 \
    if (m > bestv) { bestv = m; bestn = base + (J) * TPB; }     \
  }

__device__ __forceinline__ int read_start(const int* start, int b) {
  // start_idx dtype hedge: int64 (LE, <2^31) => zeros at odd int32 slots.
  bool is64 = true;
  #pragma unroll 1
  for (int i = 1; i < 32; i += 2) {
    if (start[i] != 0) { is64 = false; break; }
  }
  return is64 ? start[2 * b] : start[b];
}

// ---------------- fps16: 16 parts/batch, 2 blocks/CU ----------------
#define NPART16 16
#define PART_PTS16 (NPTS / NPART16)   // 8192

__global__ __launch_bounds__(TPB, 4) void fps_kernel16(
    const float* __restrict__ x, const int* __restrict__ start,
    int* __restrict__ out, unsigned long long* __restrict__ slot)
{
  #pragma clang fp contract(off)
  const int blk  = blockIdx.x;
  const int xcd  = blk & 7;
  const int j    = blk >> 3;          // 0..63
  const int b    = xcd * 4 + (j & 3); // 0..31
  const int part = j >> 2;            // 0..15
  const int tid  = threadIdx.x;
  const int lane = tid & 63;
  const int wave = tid >> 6;

  const float* xb = x + (size_t)b * (NPTS * 3);
  int cur = read_start(start, b);
  const int base = part * PART_PTS16 + tid;

  RPT16(DECLP)
  RPT16(INITP)

  __shared__ unsigned long long wred[TPB / 64];
  __shared__ int snext;

  if (part == 0 && tid == 0) out[b * KSAMP] = cur;  // scan emits idx BEFORE update

  float cx = xb[3 * (size_t)cur + 0];
  float cy = xb[3 * (size_t)cur + 1];
  float cz = xb[3 * (size_t)cur + 2];

  unsigned long long* const srow0 = slot + (size_t)b * 2 * NPART16;  // [b][2][16]

  for (int k = 0; k < KSAMP - 1; ++k) {
    float bestv = -1.0f;   // d^2 domain
    int   bestn = 0;
    RPT16(SCANP)

    const float sdw = sqrtf(bestv);   // ONE CR sqrt -> ref's sd domain

    unsigned long long key =
        ((unsigned long long)__float_as_uint(sdw) << 32) |
        (unsigned int)(NPTS - 1 - bestn);

    #pragma unroll
    for (int off = 32; off >= 1; off >>= 1) {
      unsigned long long o = __shfl_xor(key, off, 64);
      if (o > key) key = o;
    }
    if (lane == 0) wred[wave] = key;
    __syncthreads();

    if (wave == 0) {
      unsigned long long v = wred[lane & 7];
      #pragma unroll
      for (int off = 4; off >= 1; off >>= 1) {
        unsigned long long o = __shfl_xor(v, off, 64);
        if (o > v) v = o;
      }

      const unsigned tag = (unsigned)(k + 1);     // 1..2047, never 0x5555 poison
      unsigned long long* const row = srow0 + (unsigned)(k & 1) * NPART16;
      if (lane == 0)
        __hip_atomic_store(&row[part], v | ((unsigned long long)tag << 17),
                           __ATOMIC_RELAXED, __HIP_MEMORY_SCOPE_AGENT);

      unsigned long long g;
      do {
        g = __hip_atomic_load(&row[lane & (NPART16 - 1)], __ATOMIC_RELAXED,
                              __HIP_MEMORY_SCOPE_AGENT);
      } while (__ballot(((unsigned)(g >> 17) & 0x7FFFu) == tag) != ~0ull);

      #pragma unroll
      for (int off = 8; off >= 1; off >>= 1) {   // 16-slot reduce
        unsigned long long o = __shfl_xor(g, off, 64);
        if (o > g) g = o;
      }
      const int nidx = NPTS - 1 - (int)(g & 0x1FFFFu);
      if (lane == 0) {
        snext = nidx;
        if (part == 0) out[b * KSAMP + k + 1] = nidx;
      }
    }
    __syncthreads();

    const int nidx = snext;
    cx = xb[3 * (size_t)nidx + 0];
    cy = xb[3 * (size_t)nidx + 1];
    cz = xb[3 * (size_t)nidx + 2];
  }
}

// ---------------- fps32: R10 fallback (proven), 1 block/CU ----------------
#define NPART32 8
#define PART_PTS32 (NPTS / NPART32)   // 16384

__global__ __launch_bounds__(TPB)
__attribute__((amdgpu_waves_per_eu(2, 2)))
void fps_kernel32(
    const float* __restrict__ x, const int* __restrict__ start,
    int* __restrict__ out, unsigned long long* __restrict__ slot)
{
  #pragma clang fp contract(off)
  const int blk  = blockIdx.x;
  const int xcd  = blk & 7;
  const int j    = blk >> 3;          // 0..31
  const int b    = xcd * 4 + (j & 3); // 0..31
  const int part = j >> 2;            // 0..7
  const int tid  = threadIdx.x;
  const int lane = tid & 63;
  const int wave = tid >> 6;

  const float* xb = x + (size_t)b * (NPTS * 3);
  int cur = read_start(start, b);
  const int base = part * PART_PTS32 + tid;

  RPT32(DECLP)
  RPT32(INITP)

  __shared__ unsigned long long wred[TPB / 64];
  __shared__ int snext;

  if (part == 0 && tid == 0) out[b * KSAMP] = cur;

  float cx = xb[3 * (size_t)cur + 0];
  float cy = xb[3 * (size_t)cur + 1];
  float cz = xb[3 * (size_t)cur + 2];

  unsigned long long* const srow0 = slot + (size_t)b * 2 * NPART32;  // [b][2][8]

  for (int k = 0; k < KSAMP - 1; ++k) {
    float bestv = -1.0f;
    int   bestn = 0;
    RPT32(SCANP)

    const float sdw = sqrtf(bestv);

    unsigned long long key =
        ((unsigned long long)__float_as_uint(sdw) << 32) |
        (unsigned int)(NPTS - 1 - bestn);

    #pragma unroll
    for (int off = 32; off >= 1; off >>= 1) {
      unsigned long long o = __shfl_xor(key, off, 64);
      if (o > key) key = o;
    }
    if (lane == 0) wred[wave] = key;
    __syncthreads();

    if (wave == 0) {
      unsigned long long v = wred[lane & 7];
      #pragma unroll
      for (int off = 4; off >= 1; off >>= 1) {
        unsigned long long o = __shfl_xor(v, off, 64);
        if (o > v) v = o;
      }

      const unsigned tag = (unsigned)(k + 1);
      unsigned long long* const row = srow0 + (unsigned)(k & 1) * NPART32;
      if (lane == 0)
        __hip_atomic_store(&row[part], v | ((unsigned long long)tag << 17),
                           __ATOMIC_RELAXED, __HIP_MEMORY_SCOPE_AGENT);

      unsigned long long g;
      do {
        g = __hip_atomic_load(&row[lane & (NPART32 - 1)], __ATOMIC_RELAXED,
                              __HIP_MEMORY_SCOPE_AGENT);
      } while (__ballot(((unsigned)(g >> 17) & 0x7FFFu) == tag) != ~0ull);

      #pragma unroll
      for (int off = 4; off >= 1; off >>= 1) {
        unsigned long long o = __shfl_xor(g, off, 64);
        if (o > g) g = o;
      }
      const int nidx = NPTS - 1 - (int)(g & 0x1FFFFu);
      if (lane == 0) {
        snext = nidx;
        if (part == 0) out[b * KSAMP + k + 1] = nidx;
      }
    }
    __syncthreads();

    const int nidx = snext;
    cx = xb[3 * (size_t)nidx + 0];
    cy = xb[3 * (size_t)nidx + 1];
    cz = xb[3 * (size_t)nidx + 2];
  }
}

extern "C" void kernel_launch(void* const* d_in, const int* in_sizes, int n_in,
                              void* d_out, int out_size, void* d_ws, size_t ws_size,
                              hipStream_t stream) {
  const float* x     = (const float*)d_in[0];
  const int*   start = (const int*)d_in[1];
  int*         out   = (int*)d_out;
  unsigned long long* slot = (unsigned long long*)d_ws;  // <= 8KB used

  void* args[] = {(void*)&x, (void*)&start, (void*)&out, (void*)&slot};

  // Host-side occupancy check (pure query: graph-capture-safe, deterministic).
  // 512-block cooperative launch needs 2 blocks/CU co-resident; else fall
  // back to the proven 256-block kernel (R5's silent failure, explained).
  int occ = 0;
  (void)hipOccupancyMaxActiveBlocksPerMultiprocessor(
      &occ, (const void*)fps_kernel16, TPB, 0);
  if (occ >= 2) {
    hipLaunchCooperativeKernel((void*)fps_kernel16, dim3(NB * NPART16),
                               dim3(TPB), args, 0, stream);
  } else {
    hipLaunchCooperativeKernel((void*)fps_kernel32, dim3(NB * NPART32),
                               dim3(TPB), args, 0, stream);
  }
}

// Round 15
// 4623.207 us; speedup vs baseline: 1.1020x; 1.0045x over previous
//
#include <hip/hip_runtime.h>

#define NB 32
#define NPTS 131072
#define KSAMP 2048
#define NPART 8
#define TPB 512
#define NPT 32                    // points per thread = NPTS/(NPART*TPB)
#define PART_PTS (NPTS / NPART)   // 16384

// One batch = 8 blocks x 512 threads (proven cooperative grid: 256 blocks =
// 1 block/CU). Each thread owns 32 points as named scalars whose DEFINITIONS
// are volatile asm v_movs: R13 proved that pinning USES doesn't stop the RA
// from rematerializing the defining loads inside the k-loop (reload-before-
// pin is legal). A volatile-asm DEF cannot be re-executed -> the RA must
// either keep all 96 coords live in VGPRs (budget 256 via waves_per_eu(2,2),
// need ~190) or spill to scratch (visible as a one-time ~50MB WRITE_SIZE
// bump). This is the decisive residency experiment.
//
// Scan in d^2 domain (R10-validated bit-exact):
//   d2  = fma(dz,dz, fma(dx,dx, dy*dy))     (R4-validated contraction)
//   md2 = fminf(md2, d2)
// Per-thread argmax over md2 (strict >, ascending J = first-index), then ONE
// CR sqrt converts the thread winner to the reference's sd domain; the
// cross-lane/cross-block tree compares (sd_bits<<32)|(131071-n) == jnp.argmax
// value+first-index semantics over min_d.
//
// Sync per step (R6-proven): wave shfl max -> LDS -> wave0 cross-wave max ->
// tagged publish (agent store) -> wave0 spins on 64B row until all 8 tags
// match -> LDS broadcast -> barrier. No atomics, no ws zeroing (tags 1..2047
// disambiguate 0xAA poison (tag 0x5555) / stale replay data, which is
// bitwise-identical by determinism anyway; double-buffered rows kill WAR).

#define RPT32(X) X(0)X(1)X(2)X(3)X(4)X(5)X(6)X(7)X(8)X(9)X(10)X(11)X(12) \
  X(13)X(14)X(15)X(16)X(17)X(18)X(19)X(20)X(21)X(22)X(23)X(24)X(25)X(26) \
  X(27)X(28)X(29)X(30)X(31)

__global__ __launch_bounds__(TPB)
__attribute__((amdgpu_waves_per_eu(2, 2)))
void fps_kernel(
    const float* __restrict__ x, const int* __restrict__ start,
    int* __restrict__ out, unsigned long long* __restrict__ slot)
{
  #pragma clang fp contract(off)
  const int blk  = blockIdx.x;
  // XCD-clustered: all 8 parts of a batch share blk&7 (same XCD under
  // round-robin dispatch) -> sync row + x slice get L2 locality.
  const int xcd  = blk & 7;
  const int j    = blk >> 3;          // 0..31
  const int b    = xcd * 4 + (j & 3); // 0..31
  const int part = j >> 2;            // 0..7
  const int tid  = threadIdx.x;
  const int lane = tid & 63;
  const int wave = tid >> 6;

  const float* xb = x + (size_t)b * (NPTS * 3);

  // start_idx dtype hedge: int64 (LE, <2^31) => zeros at odd int32 slots.
  bool is64 = true;
  #pragma unroll 1
  for (int i = 1; i < 32; i += 2) {
    if (start[i] != 0) { is64 = false; break; }
  }
  int cur = is64 ? start[2 * b] : start[b];

  const int base = part * PART_PTS + tid;

  // 128 named scalars: px/py/pz coords + md2 running min-dist^2.
  #define DECLP(J) float px##J, py##J, pz##J, md2##J;
  RPT32(DECLP)
  #define INITP(J) { const int n = base + (J) * TPB;          \
      px##J = xb[3*n]; py##J = xb[3*n+1]; pz##J = xb[3*n+2];  \
      md2##J = __builtin_inff(); }
  RPT32(INITP)
  // Volatile-asm DEFs: non-rematerializable, non-duplicable. The RA must
  // carry these values in VGPRs across the k-loop (or pay a visible spill).
  #define PINDEF(J)                                                    \
    asm volatile("v_mov_b32 %0, %1" : "=v"(px##J) : "v"(px##J));       \
    asm volatile("v_mov_b32 %0, %1" : "=v"(py##J) : "v"(py##J));       \
    asm volatile("v_mov_b32 %0, %1" : "=v"(pz##J) : "v"(pz##J));
  RPT32(PINDEF)

  __shared__ unsigned long long wred[TPB / 64];
  __shared__ int snext;

  if (part == 0 && tid == 0) out[b * KSAMP] = cur;  // scan emits idx BEFORE update

  float cx = xb[3 * (size_t)cur + 0];
  float cy = xb[3 * (size_t)cur + 1];
  float cz = xb[3 * (size_t)cur + 2];

  unsigned long long* const srow0 = slot + (size_t)b * 2 * NPART;  // [b][2][8]

  for (int k = 0; k < KSAMP - 1; ++k) {
    float bestv = -1.0f;   // d^2 domain
    int   bestn = 0;
    #define SCANP(J) {                                              \
      const float dx = px##J - cx;                                  \
      const float dy = py##J - cy;                                  \
      const float dz = pz##J - cz;                                  \
      const float d2 = fmaf(dz, dz, fmaf(dx, dx, dy * dy));         \
      const float m  = fminf(md2##J, d2);                           \
      md2##J = m;                                                   \
      if (m > bestv) { bestv = m; bestn = base + (J) * TPB; }       \
    }
    RPT32(SCANP)

    // ONE CR sqrt per thread: convert winner to the reference's sd domain.
    const float sdw = sqrtf(bestv);

    // pack: higher sd wins; equal sd -> smaller index wins (131071-n).
    // index field bits 0..16; bits 17..31 stay 0 for the step tag.
    unsigned long long key =
        ((unsigned long long)__float_as_uint(sdw) << 32) |
        (unsigned int)(NPTS - 1 - bestn);

    #pragma unroll
    for (int off = 32; off >= 1; off >>= 1) {
      unsigned long long o = __shfl_xor(key, off, 64);
      if (o > key) key = o;
    }
    if (lane == 0) wred[wave] = key;
    __syncthreads();

    if (wave == 0) {
      // cross-wave max: lanes hold wred[lane&7]; 3 xor steps reduce each
      // aligned 8-group (all groups identical) -> block max on all lanes.
      unsigned long long v = wred[lane & 7];
      #pragma unroll
      for (int off = 4; off >= 1; off >>= 1) {
        unsigned long long o = __shfl_xor(v, off, 64);
        if (o > v) v = o;
      }

      const unsigned tag = (unsigned)(k + 1);     // 1..2047, never 0x5555 poison
      unsigned long long* const row = srow0 + (unsigned)(k & 1) * NPART;
      if (lane == 0)
        __hip_atomic_store(&row[part], v | ((unsigned long long)tag << 17),
                           __ATOMIC_RELAXED, __HIP_MEMORY_SCOPE_AGENT);

      // parallel spin on the 64B row until all 8 tags match this step.
      unsigned long long g;
      do {
        g = __hip_atomic_load(&row[lane & (NPART - 1)], __ATOMIC_RELAXED,
                              __HIP_MEMORY_SCOPE_AGENT);
      } while (__ballot(((unsigned)(g >> 17) & 0x7FFFu) == tag) != ~0ull);

      // max over 8 slots (each aligned 8-group identical): 3 xor steps.
      #pragma unroll
      for (int off = 4; off >= 1; off >>= 1) {
        unsigned long long o = __shfl_xor(g, off, 64);
        if (o > g) g = o;
      }
      const int nidx = NPTS - 1 - (int)(g & 0x1FFFFu);
      if (lane == 0) {
        snext = nidx;
        if (part == 0) out[b * KSAMP + k + 1] = nidx;
      }
    }
    __syncthreads();

    const int nidx = snext;
    cx = xb[3 * (size_t)nidx + 0];
    cy = xb[3 * (size_t)nidx + 1];
    cz = xb[3 * (size_t)nidx + 2];
  }
}

extern "C" void kernel_launch(void* const* d_in, const int* in_sizes, int n_in,
                              void* d_out, int out_size, void* d_ws, size_t ws_size,
                              hipStream_t stream) {
  const float* x     = (const float*)d_in[0];
  const int*   start = (const int*)d_in[1];
  int*         out   = (int*)d_out;
  unsigned long long* slot = (unsigned long long*)d_ws;  // [32][2][8] u64 = 4KB

  // No memset needed: step tags (1..2047 in bits 17..31) disambiguate the
  // 0xAA poison (tag 0x5555) and stale values from prior replays (which are
  // bitwise-identical across deterministic replays anyway).
  void* args[] = {(void*)&x, (void*)&start, (void*)&out, (void*)&slot};
  hipLaunchCooperativeKernel((void*)fps_kernel, dim3(NB * NPART), dim3(TPB),
                             args, 0, stream);
}